// Round 4
// baseline (1078.931 us; speedup 1.0000x reference)
//
#include <hip/hip_runtime.h>
#include <hip/hip_bf16.h>

#define N_NODES 203769
#define N_EDGES 234355
#define F_IN    165
#define F_HID   128
#define F_OUT   64
#define BN_EPS  1e-5f
#define NB_SCAN 796   // ceil(N_NODES/256)

// ---------------------------------------------------------------------------
// FMA micro-tiles: 2 rows x {8|4} cols, 4 k-steps
// ---------------------------------------------------------------------------
__device__ __forceinline__ void fma_2x8(float acc[2][8], const float4 xv[2],
                                        const float4 wa[4], const float4 wb[4]) {
#pragma unroll
    for (int r = 0; r < 2; r++) {
        const float xr[4] = {xv[r].x, xv[r].y, xv[r].z, xv[r].w};
#pragma unroll
        for (int j = 0; j < 4; j++) {
            acc[r][0] = fmaf(xr[j], wa[j].x, acc[r][0]);
            acc[r][1] = fmaf(xr[j], wa[j].y, acc[r][1]);
            acc[r][2] = fmaf(xr[j], wa[j].z, acc[r][2]);
            acc[r][3] = fmaf(xr[j], wa[j].w, acc[r][3]);
            acc[r][4] = fmaf(xr[j], wb[j].x, acc[r][4]);
            acc[r][5] = fmaf(xr[j], wb[j].y, acc[r][5]);
            acc[r][6] = fmaf(xr[j], wb[j].z, acc[r][6]);
            acc[r][7] = fmaf(xr[j], wb[j].w, acc[r][7]);
        }
    }
}

__device__ __forceinline__ void fma_2x4(float acc[2][4], const float4 xv[2],
                                        const float4 w[4]) {
#pragma unroll
    for (int r = 0; r < 2; r++) {
        const float xr[4] = {xv[r].x, xv[r].y, xv[r].z, xv[r].w};
#pragma unroll
        for (int j = 0; j < 4; j++) {
            acc[r][0] = fmaf(xr[j], w[j].x, acc[r][0]);
            acc[r][1] = fmaf(xr[j], w[j].y, acc[r][1]);
            acc[r][2] = fmaf(xr[j], w[j].z, acc[r][2]);
            acc[r][3] = fmaf(xr[j], w[j].w, acc[r][3]);
        }
    }
}

// ---------------------------------------------------------------------------
// CSR build
// ---------------------------------------------------------------------------
__global__ void k_count(const int* __restrict__ dst, int* __restrict__ cnt) {
    int e = blockIdx.x * 256 + threadIdx.x;
    if (e < N_EDGES) atomicAdd(&cnt[dst[e]], 1);
}

__global__ __launch_bounds__(256) void k_scanA(const int* __restrict__ cnt,
                                               int* __restrict__ partials) {
    __shared__ int sm[256];
    int t = threadIdx.x;
    int i = blockIdx.x * 256 + t;
    int v = (i < N_NODES) ? cnt[i] : 0;
    sm[t] = v;
    __syncthreads();
    for (int off = 128; off > 0; off >>= 1) {
        if (t < off) sm[t] += sm[t + off];
        __syncthreads();
    }
    if (t == 0) partials[blockIdx.x] = sm[0];
}

__global__ __launch_bounds__(1024) void k_scanB(int* __restrict__ partials,
                                                int* __restrict__ row_ptr) {
    __shared__ int sm[1024];
    int t = threadIdx.x;
    int v = (t < NB_SCAN) ? partials[t] : 0;
    sm[t] = v;
    __syncthreads();
    for (int off = 1; off < 1024; off <<= 1) {
        int add = (t >= off) ? sm[t - off] : 0;
        __syncthreads();
        sm[t] += add;
        __syncthreads();
    }
    if (t < NB_SCAN) partials[t] = sm[t] - v;   // exclusive
    if (t == NB_SCAN - 1) row_ptr[N_NODES] = sm[t];  // = E
}

__global__ __launch_bounds__(256) void k_scanC(const int* __restrict__ cnt,
                                               const int* __restrict__ partials,
                                               int* __restrict__ row_ptr,
                                               int* __restrict__ cursor,
                                               float* __restrict__ dinv) {
    __shared__ int sm[256];
    int t = threadIdx.x;
    int i = blockIdx.x * 256 + t;
    int v = (i < N_NODES) ? cnt[i] : 0;
    sm[t] = v;
    __syncthreads();
    for (int off = 1; off < 256; off <<= 1) {
        int add = (t >= off) ? sm[t - off] : 0;
        __syncthreads();
        sm[t] += add;
        __syncthreads();
    }
    if (i < N_NODES) {
        int p = partials[blockIdx.x] + sm[t] - v;  // exclusive prefix
        row_ptr[i] = p;
        cursor[i] = p;
        dinv[i] = rsqrtf(1.0f + (float)v);  // +1 self loop
    }
}

__global__ void k_scatter(const int* __restrict__ src, const int* __restrict__ dst,
                          int* __restrict__ cursor, int* __restrict__ csr_src) {
    int e = blockIdx.x * 256 + threadIdx.x;
    if (e < N_EDGES) {
        int pos = atomicAdd(&cursor[dst[e]], 1);
        csr_src[pos] = src[e];
    }
}

// ---------------------------------------------------------------------------
// GEMM1: h1s[N,128] = (x[N,165] @ W1[165,128]) * dinv[row]
// 512 threads, 64-row tile (LDS 43KB), thread = 2r x 8c.
// Ping-pong W prefetch (regs A/B) hides L1/L2 latency; unroll 1 pins rotation.
// launch_bounds(512,4) caps VGPR at 128 -> 16 waves/CU.
// ---------------------------------------------------------------------------
__global__ __launch_bounds__(512, 4) void k_gemm1(const float* __restrict__ x,
                                                  const float* __restrict__ W1,
                                                  const float* __restrict__ dinv,
                                                  float* __restrict__ h1s) {
    __shared__ float xs[64 * 168];  // 43 KB
    const int row0 = blockIdx.x * 64;
    const int t = threadIdx.x;
    {
        const float* src = x + (size_t)row0 * F_IN;
        const int maxe = (N_NODES - row0) * F_IN;
        for (int fi = t; fi < 64 * F_IN; fi += 512) {
            int r = fi / F_IN;
            int k = fi - r * F_IN;
            xs[r * 168 + k] = (fi < maxe) ? src[fi] : 0.0f;
        }
    }
    __syncthreads();

    const int c0 = (t & 15) * 8;
    const int r0 = (t >> 4) * 2;
    const float* xrow0 = &xs[r0 * 168];
    const float* xrow1 = &xs[(r0 + 1) * 168];

    float acc[2][8];
#pragma unroll
    for (int r = 0; r < 2; r++)
#pragma unroll
        for (int c = 0; c < 8; c++) acc[r][c] = 0.0f;

    float4 waA[4], wbA[4], waB[4], wbB[4];
#pragma unroll
    for (int j = 0; j < 4; j++) {
        waA[j] = *(const float4*)&W1[j * F_HID + c0];
        wbA[j] = *(const float4*)&W1[j * F_HID + c0 + 4];
    }

#pragma unroll 1
    for (int k4 = 0; k4 < 160; k4 += 8) {
#pragma unroll
        for (int j = 0; j < 4; j++) {
            waB[j] = *(const float4*)&W1[(k4 + 4 + j) * F_HID + c0];
            wbB[j] = *(const float4*)&W1[(k4 + 4 + j) * F_HID + c0 + 4];
        }
        float4 xv[2] = {*(const float4*)&xrow0[k4], *(const float4*)&xrow1[k4]};
        fma_2x8(acc, xv, waA, wbA);
#pragma unroll
        for (int j = 0; j < 4; j++) {
            waA[j] = *(const float4*)&W1[(k4 + 8 + j) * F_HID + c0];
            wbA[j] = *(const float4*)&W1[(k4 + 8 + j) * F_HID + c0 + 4];
        }
        float4 xw[2] = {*(const float4*)&xrow0[k4 + 4], *(const float4*)&xrow1[k4 + 4]};
        fma_2x8(acc, xw, waB, wbB);
    }
    {   // k = 160..163 (already in A regs)
        float4 xv[2] = {*(const float4*)&xrow0[160], *(const float4*)&xrow1[160]};
        fma_2x8(acc, xv, waA, wbA);
    }
    {   // k = 164
        float4 wa = *(const float4*)&W1[164 * F_HID + c0];
        float4 wb = *(const float4*)&W1[164 * F_HID + c0 + 4];
#pragma unroll
        for (int r = 0; r < 2; r++) {
            float xr = xs[(r0 + r) * 168 + 164];
            acc[r][0] = fmaf(xr, wa.x, acc[r][0]);
            acc[r][1] = fmaf(xr, wa.y, acc[r][1]);
            acc[r][2] = fmaf(xr, wa.z, acc[r][2]);
            acc[r][3] = fmaf(xr, wa.w, acc[r][3]);
            acc[r][4] = fmaf(xr, wb.x, acc[r][4]);
            acc[r][5] = fmaf(xr, wb.y, acc[r][5]);
            acc[r][6] = fmaf(xr, wb.z, acc[r][6]);
            acc[r][7] = fmaf(xr, wb.w, acc[r][7]);
        }
    }
#pragma unroll
    for (int r = 0; r < 2; r++) {
        int row = row0 + r0 + r;
        if (row < N_NODES) {
            float dv = dinv[row];
            float4 o0 = {acc[r][0] * dv, acc[r][1] * dv, acc[r][2] * dv, acc[r][3] * dv};
            float4 o1 = {acc[r][4] * dv, acc[r][5] * dv, acc[r][6] * dv, acc[r][7] * dv};
            *(float4*)&h1s[(size_t)row * F_HID + c0]     = o0;
            *(float4*)&h1s[(size_t)row * F_HID + c0 + 4] = o1;
        }
    }
}

// ---------------------------------------------------------------------------
// CSR aggregation + fused BN stats (unchanged):
// out[d,:] = dinv[d] * (hs[d,:] + sum_{s in in(d)} hs[s,:])
// ---------------------------------------------------------------------------
template <int C, int TPN, int NPB>
__global__ __launch_bounds__(256) void k_aggr(const float* __restrict__ hs,
                                              const int* __restrict__ row_ptr,
                                              const int* __restrict__ csr_src,
                                              const float* __restrict__ dinv,
                                              float* __restrict__ out,
                                              float* __restrict__ gsum,
                                              float* __restrict__ gsumsq) {
    const int t = threadIdx.x;
    const int q = t & (TPN - 1);
    const int slot = t / TPN;
    float s0 = 0, s1 = 0, s2 = 0, s3 = 0;
    float q0 = 0, q1 = 0, q2 = 0, q3 = 0;

    for (int node = blockIdx.x * NPB + slot; node < N_NODES;
         node += gridDim.x * NPB) {
        int beg = row_ptr[node];
        int end = row_ptr[node + 1];
        float4 acc = *(const float4*)&hs[(size_t)node * C + q * 4];
        for (int e = beg; e < end; e++) {
            int s = csr_src[e];
            float4 v = *(const float4*)&hs[(size_t)s * C + q * 4];
            acc.x += v.x; acc.y += v.y; acc.z += v.z; acc.w += v.w;
        }
        float dv = dinv[node];
        acc.x *= dv; acc.y *= dv; acc.z *= dv; acc.w *= dv;
        *(float4*)&out[(size_t)node * C + q * 4] = acc;
        s0 += acc.x; s1 += acc.y; s2 += acc.z; s3 += acc.w;
        q0 = fmaf(acc.x, acc.x, q0); q1 = fmaf(acc.y, acc.y, q1);
        q2 = fmaf(acc.z, acc.z, q2); q3 = fmaf(acc.w, acc.w, q3);
    }

    __shared__ float sm[256 * 4];
    __shared__ float sq[256 * 4];
    sm[t * 4 + 0] = s0; sm[t * 4 + 1] = s1; sm[t * 4 + 2] = s2; sm[t * 4 + 3] = s3;
    sq[t * 4 + 0] = q0; sq[t * 4 + 1] = q1; sq[t * 4 + 2] = q2; sq[t * 4 + 3] = q3;
    __syncthreads();
    if (t < TPN) {
#pragma unroll
        for (int sl = 1; sl < NPB; sl++) {
            int u = (sl * TPN + t) * 4;
            s0 += sm[u + 0]; s1 += sm[u + 1]; s2 += sm[u + 2]; s3 += sm[u + 3];
            q0 += sq[u + 0]; q1 += sq[u + 1]; q2 += sq[u + 2]; q3 += sq[u + 3];
        }
        atomicAdd(&gsum[t * 4 + 0], s0); atomicAdd(&gsum[t * 4 + 1], s1);
        atomicAdd(&gsum[t * 4 + 2], s2); atomicAdd(&gsum[t * 4 + 3], s3);
        atomicAdd(&gsumsq[t * 4 + 0], q0); atomicAdd(&gsumsq[t * 4 + 1], q1);
        atomicAdd(&gsumsq[t * 4 + 2], q2); atomicAdd(&gsumsq[t * 4 + 3], q3);
    }
}

// scale = g*rstd ; shift = be - mean*scale
__global__ void k_bn_finalize(const float* gsum, const float* gsumsq,
                              const float* g, const float* be,
                              float* sc, float* sh, int C) {
    int c = threadIdx.x;
    if (c < C) {
        const float invn = 1.0f / (float)N_NODES;
        float mean = gsum[c] * invn;
        float var = gsumsq[c] * invn - mean * mean;
        float rstd = rsqrtf(var + BN_EPS);
        float scale = g[c] * rstd;
        sc[c] = scale;
        sh[c] = fmaf(-mean, scale, be[c]);
    }
}

// ---------------------------------------------------------------------------
// GEMM2: h2s[N,64] = (relu(bn1(out1[N,128])) @ W2[128,64]) * dinv[row]
// 512 threads, 64-row tile (LDS 33.8KB, stride 132), thread = 2r x 4c,
// ping-pong W2 prefetch.
// ---------------------------------------------------------------------------
__global__ __launch_bounds__(512, 4) void k_gemm2(const float* __restrict__ out1,
                                                  const float* __restrict__ sc1,
                                                  const float* __restrict__ sh1,
                                                  const float* __restrict__ W2,
                                                  const float* __restrict__ dinv,
                                                  float* __restrict__ h2s) {
    __shared__ float xs[64 * 132];  // 33.8 KB
    const int row0 = blockIdx.x * 64;
    const int t = threadIdx.x;
    {
        const float4* src = (const float4*)(out1 + (size_t)row0 * F_HID);
        const int maxf4 = (N_NODES - row0) * 32;
#pragma unroll
        for (int i = 0; i < 4; i++) {
            int f4 = t + i * 512;      // 0..2047
            int r = f4 >> 5;
            int c4 = f4 & 31;
            float4 v = {0, 0, 0, 0};
            if (f4 < maxf4) v = src[f4];
            int c = c4 * 4;
            float4 s = *(const float4*)&sc1[c];
            float4 h = *(const float4*)&sh1[c];
            v.x = fmaxf(fmaf(v.x, s.x, h.x), 0.0f);
            v.y = fmaxf(fmaf(v.y, s.y, h.y), 0.0f);
            v.z = fmaxf(fmaf(v.z, s.z, h.z), 0.0f);
            v.w = fmaxf(fmaf(v.w, s.w, h.w), 0.0f);
            *(float4*)&xs[r * 132 + c] = v;
        }
    }
    __syncthreads();

    const int c0 = (t & 15) * 4;
    const int r0 = (t >> 4) * 2;
    const float* xrow0 = &xs[r0 * 132];
    const float* xrow1 = &xs[(r0 + 1) * 132];

    float acc[2][4];
#pragma unroll
    for (int r = 0; r < 2; r++)
#pragma unroll
        for (int c = 0; c < 4; c++) acc[r][c] = 0.0f;

    float4 wA[4], wB[4];
#pragma unroll
    for (int j = 0; j < 4; j++)
        wA[j] = *(const float4*)&W2[j * F_OUT + c0];

#pragma unroll 1
    for (int k4 = 0; k4 < 120; k4 += 8) {
#pragma unroll
        for (int j = 0; j < 4; j++)
            wB[j] = *(const float4*)&W2[(k4 + 4 + j) * F_OUT + c0];
        float4 xv[2] = {*(const float4*)&xrow0[k4], *(const float4*)&xrow1[k4]};
        fma_2x4(acc, xv, wA);
#pragma unroll
        for (int j = 0; j < 4; j++)
            wA[j] = *(const float4*)&W2[(k4 + 8 + j) * F_OUT + c0];
        float4 xw[2] = {*(const float4*)&xrow0[k4 + 4], *(const float4*)&xrow1[k4 + 4]};
        fma_2x4(acc, xw, wB);
    }
    {   // k = 120..127
#pragma unroll
        for (int j = 0; j < 4; j++)
            wB[j] = *(const float4*)&W2[(124 + j) * F_OUT + c0];
        float4 xv[2] = {*(const float4*)&xrow0[120], *(const float4*)&xrow1[120]};
        fma_2x4(acc, xv, wA);
        float4 xw[2] = {*(const float4*)&xrow0[124], *(const float4*)&xrow1[124]};
        fma_2x4(acc, xw, wB);
    }
#pragma unroll
    for (int r = 0; r < 2; r++) {
        int row = row0 + r0 + r;
        if (row < N_NODES) {
            float dv = dinv[row];
            float4 o = {acc[r][0] * dv, acc[r][1] * dv, acc[r][2] * dv, acc[r][3] * dv};
            *(float4*)&h2s[(size_t)row * F_OUT + c0] = o;
        }
    }
}

// ---------------------------------------------------------------------------
// Final: hf = bn2(out2) -> d_out[0:N*64]; z = relu(hf@Wp1+bp1)@Wp2+bp2 -> rest
// 512 threads, 64-row tile, thread = 2r x 4c, ping-pong weight prefetch.
// ---------------------------------------------------------------------------
__global__ __launch_bounds__(512, 4) void k_final(const float* __restrict__ out2,
                                                  const float* __restrict__ sc2,
                                                  const float* __restrict__ sh2,
                                                  const float* __restrict__ Wp1,
                                                  const float* __restrict__ bp1,
                                                  const float* __restrict__ Wp2,
                                                  const float* __restrict__ bp2,
                                                  float* __restrict__ out) {
    __shared__ float hs[64 * 68];   // 17.4 KB
    __shared__ float as_[64 * 68];  // 17.4 KB
    const int row0 = blockIdx.x * 64;
    const int t = threadIdx.x;

    {   // stage: BN2-apply, write h output, keep in LDS
        const float4* src = (const float4*)out2;
        float4* dsth = (float4*)out;
#pragma unroll
        for (int i = 0; i < 2; i++) {
            int f4 = t + i * 512;       // 0..1023
            int r = f4 >> 4;
            int c4 = f4 & 15;
            int grow = row0 + r;
            float4 v = {0, 0, 0, 0};
            if (grow < N_NODES) v = src[(size_t)grow * 16 + c4];
            int c = c4 * 4;
            float4 s = *(const float4*)&sc2[c];
            float4 h = *(const float4*)&sh2[c];
            v.x = fmaf(v.x, s.x, h.x);
            v.y = fmaf(v.y, s.y, h.y);
            v.z = fmaf(v.z, s.z, h.z);
            v.w = fmaf(v.w, s.w, h.w);
            if (grow < N_NODES) dsth[(size_t)grow * 16 + c4] = v;
            *(float4*)&hs[r * 68 + c] = v;
        }
    }
    __syncthreads();

    const int c0 = (t & 15) * 4;
    const int r0 = (t >> 4) * 2;

    // GEMM A: a = relu(hs @ Wp1 + bp1) -> as_
    {
        const float* xrow0 = &hs[r0 * 68];
        const float* xrow1 = &hs[(r0 + 1) * 68];
        float acc[2][4];
#pragma unroll
        for (int r = 0; r < 2; r++)
#pragma unroll
            for (int c = 0; c < 4; c++) acc[r][c] = 0.0f;
        float4 wA[4], wB[4];
#pragma unroll
        for (int j = 0; j < 4; j++)
            wA[j] = *(const float4*)&Wp1[j * 64 + c0];
#pragma unroll 1
        for (int k4 = 0; k4 < 56; k4 += 8) {
#pragma unroll
            for (int j = 0; j < 4; j++)
                wB[j] = *(const float4*)&Wp1[(k4 + 4 + j) * 64 + c0];
            float4 xv[2] = {*(const float4*)&xrow0[k4], *(const float4*)&xrow1[k4]};
            fma_2x4(acc, xv, wA);
#pragma unroll
            for (int j = 0; j < 4; j++)
                wA[j] = *(const float4*)&Wp1[(k4 + 8 + j) * 64 + c0];
            float4 xw[2] = {*(const float4*)&xrow0[k4 + 4], *(const float4*)&xrow1[k4 + 4]};
            fma_2x4(acc, xw, wB);
        }
        {
#pragma unroll
            for (int j = 0; j < 4; j++)
                wB[j] = *(const float4*)&Wp1[(60 + j) * 64 + c0];
            float4 xv[2] = {*(const float4*)&xrow0[56], *(const float4*)&xrow1[56]};
            fma_2x4(acc, xv, wA);
            float4 xw[2] = {*(const float4*)&xrow0[60], *(const float4*)&xrow1[60]};
            fma_2x4(acc, xw, wB);
        }
        float4 b = *(const float4*)&bp1[c0];
#pragma unroll
        for (int r = 0; r < 2; r++) {
            float4 o = {fmaxf(acc[r][0] + b.x, 0.0f), fmaxf(acc[r][1] + b.y, 0.0f),
                        fmaxf(acc[r][2] + b.z, 0.0f), fmaxf(acc[r][3] + b.w, 0.0f)};
            *(float4*)&as_[(r0 + r) * 68 + c0] = o;
        }
    }
    __syncthreads();

    // GEMM B: z = a @ Wp2 + bp2
    {
        const float* xrow0 = &as_[r0 * 68];
        const float* xrow1 = &as_[(r0 + 1) * 68];
        float acc[2][4];
#pragma unroll
        for (int r = 0; r < 2; r++)
#pragma unroll
            for (int c = 0; c < 4; c++) acc[r][c] = 0.0f;
        float4 wA[4], wB[4];
#pragma unroll
        for (int j = 0; j < 4; j++)
            wA[j] = *(const float4*)&Wp2[j * 64 + c0];
#pragma unroll 1
        for (int k4 = 0; k4 < 56; k4 += 8) {
#pragma unroll
            for (int j = 0; j < 4; j++)
                wB[j] = *(const float4*)&Wp2[(k4 + 4 + j) * 64 + c0];
            float4 xv[2] = {*(const float4*)&xrow0[k4], *(const float4*)&xrow1[k4]};
            fma_2x4(acc, xv, wA);
#pragma unroll
            for (int j = 0; j < 4; j++)
                wA[j] = *(const float4*)&Wp2[(k4 + 8 + j) * 64 + c0];
            float4 xw[2] = {*(const float4*)&xrow0[k4 + 4], *(const float4*)&xrow1[k4 + 4]};
            fma_2x4(acc, xw, wB);
        }
        {
#pragma unroll
            for (int j = 0; j < 4; j++)
                wB[j] = *(const float4*)&Wp2[(60 + j) * 64 + c0];
            float4 xv[2] = {*(const float4*)&xrow0[56], *(const float4*)&xrow1[56]};
            fma_2x4(acc, xv, wA);
            float4 xw[2] = {*(const float4*)&xrow0[60], *(const float4*)&xrow1[60]};
            fma_2x4(acc, xw, wB);
        }
        float4 b = *(const float4*)&bp2[c0];
        float* zout = out + (size_t)N_NODES * 64;
#pragma unroll
        for (int r = 0; r < 2; r++) {
            int row = row0 + r0 + r;
            if (row < N_NODES) {
                float4 o = {acc[r][0] + b.x, acc[r][1] + b.y,
                            acc[r][2] + b.z, acc[r][3] + b.w};
                *(float4*)&zout[(size_t)row * 64 + c0] = o;
            }
        }
    }
}

// ---------------------------------------------------------------------------
// launch
// ---------------------------------------------------------------------------
extern "C" void kernel_launch(void* const* d_in, const int* in_sizes, int n_in,
                              void* d_out, int out_size, void* d_ws, size_t ws_size,
                              hipStream_t stream) {
    const float* x   = (const float*)d_in[0];
    const int*   ei  = (const int*)d_in[1];
    const float* W1  = (const float*)d_in[2];
    // b1 (d_in[3]) skipped: column-constant shift cancelled by BN1
    const float* g1  = (const float*)d_in[4];
    const float* be1 = (const float*)d_in[5];
    const float* W2  = (const float*)d_in[6];
    // b2 (d_in[7]) skipped: cancelled by BN2
    const float* g2  = (const float*)d_in[8];
    const float* be2 = (const float*)d_in[9];
    const float* Wp1 = (const float*)d_in[10];
    const float* bp1 = (const float*)d_in[11];
    const float* Wp2 = (const float*)d_in[12];
    const float* bp2 = (const float*)d_in[13];

    const int* src = ei;            // edge_index[0]
    const int* dst = ei + N_EDGES;  // edge_index[1]

    float* ws = (float*)d_ws;
    float* A    = ws;                          // h1s (N*128) / h2s (N*64)
    float* B    = A + (size_t)N_NODES * 128;   // out1 (N*128) / out2 (N*64)
    float* dinv = B + (size_t)N_NODES * 128;   // N
    float* st   = dinv + N_NODES;              // 768 floats of stats
    float* s1   = st;        float* s1q  = st + 128;
    float* sc1  = st + 256;  float* sh1  = st + 384;
    float* s2   = st + 512;  float* s2q  = st + 576;
    float* sc2  = st + 640;  float* sh2  = st + 704;
    int* cnt      = (int*)(st + 768);          // N
    int* row_ptr  = cnt + N_NODES;             // N+1
    int* cursor   = row_ptr + N_NODES + 1;     // N
    int* csr_src  = cursor + N_NODES;          // E
    int* partials = csr_src + N_EDGES;         // NB_SCAN

    hipMemsetAsync(st, 0, (768 + N_NODES) * sizeof(float), stream);

    const int EB = (N_EDGES + 255) / 256;
    const int GB = (N_NODES + 63) / 64;

    // CSR build + dinv
    k_count<<<EB, 256, 0, stream>>>(dst, cnt);
    k_scanA<<<NB_SCAN, 256, 0, stream>>>(cnt, partials);
    k_scanB<<<1, 1024, 0, stream>>>(partials, row_ptr);
    k_scanC<<<NB_SCAN, 256, 0, stream>>>(cnt, partials, row_ptr, cursor, dinv);
    k_scatter<<<EB, 256, 0, stream>>>(src, dst, cursor, csr_src);

    // layer 1
    k_gemm1<<<GB, 512, 0, stream>>>(x, W1, dinv, A);
    k_aggr<128, 32, 8><<<1024, 256, 0, stream>>>(A, row_ptr, csr_src, dinv, B, s1, s1q);
    k_bn_finalize<<<1, 128, 0, stream>>>(s1, s1q, g1, be1, sc1, sh1, 128);

    // layer 2 (BN1+relu fused into GEMM2 load)
    k_gemm2<<<GB, 512, 0, stream>>>(B, sc1, sh1, W2, dinv, A);
    k_aggr<64, 16, 16><<<1024, 256, 0, stream>>>(A, row_ptr, csr_src, dinv, B, s2, s2q);
    k_bn_finalize<<<1, 64, 0, stream>>>(s2, s2q, g2, be2, sc2, sh2, 64);

    // BN2-apply + MLP head, writes both outputs
    k_final<<<GB, 512, 0, stream>>>(B, sc2, sh2, Wp1, bp1, Wp2, bp2, (float*)d_out);
}

// Round 5
// 882.656 us; speedup vs baseline: 1.2224x; 1.2224x over previous
//
#include <hip/hip_runtime.h>
#include <hip/hip_bf16.h>

#define N_NODES 203769
#define N_EDGES 234355
#define F_IN    165
#define F_HID   128
#define F_OUT   64
#define BN_EPS  1e-5f
#define NB_SCAN 796   // ceil(N_NODES/256)
#define KP      192   // K padded to 6*32 for mfma_16x16x32
#define XST     104   // LDS row stride in shorts (208B = 52 dwords -> 2-way banks, free)

typedef short bf16x8 __attribute__((ext_vector_type(8)));
typedef unsigned short u16x8 __attribute__((ext_vector_type(8)));
typedef float f32x4 __attribute__((ext_vector_type(4)));

__device__ __forceinline__ unsigned short f2bf(float f) {
    unsigned int u = __builtin_bit_cast(unsigned int, f);
    u += 0x7fffu + ((u >> 16) & 1u);   // RNE
    return (unsigned short)(u >> 16);
}

// ---------------------------------------------------------------------------
// CSR build
// ---------------------------------------------------------------------------
__global__ void k_count(const int* __restrict__ dst, int* __restrict__ cnt) {
    int e = blockIdx.x * 256 + threadIdx.x;
    if (e < N_EDGES) atomicAdd(&cnt[dst[e]], 1);
}

__global__ __launch_bounds__(256) void k_scanA(const int* __restrict__ cnt,
                                               int* __restrict__ partials) {
    __shared__ int sm[256];
    int t = threadIdx.x;
    int i = blockIdx.x * 256 + t;
    int v = (i < N_NODES) ? cnt[i] : 0;
    sm[t] = v;
    __syncthreads();
    for (int off = 128; off > 0; off >>= 1) {
        if (t < off) sm[t] += sm[t + off];
        __syncthreads();
    }
    if (t == 0) partials[blockIdx.x] = sm[0];
}

__global__ __launch_bounds__(1024) void k_scanB(int* __restrict__ partials,
                                                int* __restrict__ row_ptr) {
    __shared__ int sm[1024];
    int t = threadIdx.x;
    int v = (t < NB_SCAN) ? partials[t] : 0;
    sm[t] = v;
    __syncthreads();
    for (int off = 1; off < 1024; off <<= 1) {
        int add = (t >= off) ? sm[t - off] : 0;
        __syncthreads();
        sm[t] += add;
        __syncthreads();
    }
    if (t < NB_SCAN) partials[t] = sm[t] - v;   // exclusive
    if (t == NB_SCAN - 1) row_ptr[N_NODES] = sm[t];  // = E
}

__global__ __launch_bounds__(256) void k_scanC(const int* __restrict__ cnt,
                                               const int* __restrict__ partials,
                                               int* __restrict__ row_ptr,
                                               int* __restrict__ cursor,
                                               float* __restrict__ dinv) {
    __shared__ int sm[256];
    int t = threadIdx.x;
    int i = blockIdx.x * 256 + t;
    int v = (i < N_NODES) ? cnt[i] : 0;
    sm[t] = v;
    __syncthreads();
    for (int off = 1; off < 256; off <<= 1) {
        int add = (t >= off) ? sm[t - off] : 0;
        __syncthreads();
        sm[t] += add;
        __syncthreads();
    }
    if (i < N_NODES) {
        int p = partials[blockIdx.x] + sm[t] - v;  // exclusive prefix
        row_ptr[i] = p;
        cursor[i] = p;
        dinv[i] = rsqrtf(1.0f + (float)v);  // +1 self loop
    }
}

__global__ void k_scatter(const int* __restrict__ src, const int* __restrict__ dst,
                          int* __restrict__ cursor, int* __restrict__ csr_src) {
    int e = blockIdx.x * 256 + threadIdx.x;
    if (e < N_EDGES) {
        int pos = atomicAdd(&cursor[dst[e]], 1);
        csr_src[pos] = src[e];
    }
}

// ---------------------------------------------------------------------------
// W1 -> bf16 transposed: w1t[n][k], n=0..127, k=0..191 (zero-pad k>=165)
// ---------------------------------------------------------------------------
__global__ void k_cvt_w(const float* __restrict__ W1, unsigned short* __restrict__ w1t) {
    int i = blockIdx.x * 256 + threadIdx.x;
    if (i < F_HID * KP) {
        int n = i / KP, k = i - n * KP;
        float v = (k < F_IN) ? W1[k * F_HID + n] : 0.0f;
        w1t[i] = f2bf(v);
    }
}

// ---------------------------------------------------------------------------
// GEMM1 via bf16 MFMA: h1s[N,128] = (x[N,165] @ W1[165,128]) * dinv[row]
// Block = 128 rows x 128 cols, 256 thr (4 waves, each 64x64 = 4x4 mfma tiles).
// Two K-chunks of 96; x converted fp32->bf16 during staging; W1 from w1t.
// Layouts (HW-verified): A[m=lane&15][k=quad*8+j]; C/D col=lane&15,
// row=quad*4+reg. R4 post-mortem: fp32 version was VMEM-bound on redundant
// W loads; bf16 LDS-resident W removes them.
// ---------------------------------------------------------------------------
__global__ __launch_bounds__(256) void k_mfma1(const float* __restrict__ x,
                                               const unsigned short* __restrict__ w1t,
                                               const float* __restrict__ dinv,
                                               float* __restrict__ h1s) {
    __shared__ unsigned short xs[128 * XST];   // 26 KB
    __shared__ unsigned short wsh[128 * XST];  // 26 KB
    const int row0 = blockIdx.x * 128;
    const int t = threadIdx.x;
    const int lane = t & 63;
    const int wv = t >> 6;
    const int l16 = lane & 15;
    const int quad = lane >> 4;
    const int m0w = (wv >> 1) * 64;
    const int n0w = (wv & 1) * 64;

    f32x4 acc[4][4];
#pragma unroll
    for (int mt = 0; mt < 4; mt++)
#pragma unroll
        for (int nt = 0; nt < 4; nt++)
            acc[mt][nt] = (f32x4){0.0f, 0.0f, 0.0f, 0.0f};

    for (int cc = 0; cc < 2; cc++) {
        const int kc = cc * 96;
        // stage x chunk (fp32 -> bf16)
#pragma unroll
        for (int s = 0; s < 6; s++) {
            int g = t + s * 256;          // 0..1535
            int r = g / 12;
            int c8 = (g - r * 12) * 8;    // 0,8,...,88
            int grow = row0 + r;
            u16x8 uv;
            if (grow < N_NODES) {
                const float* xr = x + (size_t)grow * F_IN;
#pragma unroll
                for (int j = 0; j < 8; j++) {
                    int k = kc + c8 + j;
                    uv[j] = (k < F_IN) ? f2bf(xr[k]) : (unsigned short)0;
                }
            } else {
#pragma unroll
                for (int j = 0; j < 8; j++) uv[j] = 0;
            }
            *(u16x8*)&xs[r * XST + c8] = uv;
        }
        // stage w chunk (already bf16)
#pragma unroll
        for (int s = 0; s < 6; s++) {
            int g = t + s * 256;
            int r = g / 12;
            int c8 = (g - r * 12) * 8;
            *(u16x8*)&wsh[r * XST + c8] = *(const u16x8*)&w1t[r * KP + kc + c8];
        }
        __syncthreads();

#pragma unroll
        for (int ks = 0; ks < 96; ks += 32) {
            int kf = ks + quad * 8;
            bf16x8 a[4], b[4];
#pragma unroll
            for (int mt = 0; mt < 4; mt++)
                a[mt] = *(const bf16x8*)&xs[(m0w + mt * 16 + l16) * XST + kf];
#pragma unroll
            for (int nt = 0; nt < 4; nt++)
                b[nt] = *(const bf16x8*)&wsh[(n0w + nt * 16 + l16) * XST + kf];
#pragma unroll
            for (int mt = 0; mt < 4; mt++)
#pragma unroll
                for (int nt = 0; nt < 4; nt++)
                    acc[mt][nt] = __builtin_amdgcn_mfma_f32_16x16x32_bf16(
                        a[mt], b[nt], acc[mt][nt], 0, 0, 0);
        }
        __syncthreads();
    }

    // epilogue: C/D col = lane&15, row = quad*4 + reg; scale by dinv[row]
#pragma unroll
    for (int mt = 0; mt < 4; mt++) {
#pragma unroll
        for (int rg = 0; rg < 4; rg++) {
            int grow = row0 + m0w + mt * 16 + quad * 4 + rg;
            if (grow < N_NODES) {
                float dv = dinv[grow];
                float* orow = h1s + (size_t)grow * F_HID + n0w + l16;
#pragma unroll
                for (int nt = 0; nt < 4; nt++)
                    orow[nt * 16] = acc[mt][nt][rg] * dv;
            }
        }
    }
}

// ---------------------------------------------------------------------------
// CSR aggregation + fused BN stats:
// out[d,:] = dinv[d] * (hs[d,:] + sum_{s in in(d)} hs[s,:])
// ---------------------------------------------------------------------------
template <int C, int TPN, int NPB>
__global__ __launch_bounds__(256) void k_aggr(const float* __restrict__ hs,
                                              const int* __restrict__ row_ptr,
                                              const int* __restrict__ csr_src,
                                              const float* __restrict__ dinv,
                                              float* __restrict__ out,
                                              float* __restrict__ gsum,
                                              float* __restrict__ gsumsq) {
    const int t = threadIdx.x;
    const int q = t & (TPN - 1);
    const int slot = t / TPN;
    float s0 = 0, s1 = 0, s2 = 0, s3 = 0;
    float q0 = 0, q1 = 0, q2 = 0, q3 = 0;

    for (int node = blockIdx.x * NPB + slot; node < N_NODES;
         node += gridDim.x * NPB) {
        int beg = row_ptr[node];
        int end = row_ptr[node + 1];
        float4 acc = *(const float4*)&hs[(size_t)node * C + q * 4];
        for (int e = beg; e < end; e++) {
            int s = csr_src[e];
            float4 v = *(const float4*)&hs[(size_t)s * C + q * 4];
            acc.x += v.x; acc.y += v.y; acc.z += v.z; acc.w += v.w;
        }
        float dv = dinv[node];
        acc.x *= dv; acc.y *= dv; acc.z *= dv; acc.w *= dv;
        *(float4*)&out[(size_t)node * C + q * 4] = acc;
        s0 += acc.x; s1 += acc.y; s2 += acc.z; s3 += acc.w;
        q0 = fmaf(acc.x, acc.x, q0); q1 = fmaf(acc.y, acc.y, q1);
        q2 = fmaf(acc.z, acc.z, q2); q3 = fmaf(acc.w, acc.w, q3);
    }

    __shared__ float sm[256 * 4];
    __shared__ float sq[256 * 4];
    sm[t * 4 + 0] = s0; sm[t * 4 + 1] = s1; sm[t * 4 + 2] = s2; sm[t * 4 + 3] = s3;
    sq[t * 4 + 0] = q0; sq[t * 4 + 1] = q1; sq[t * 4 + 2] = q2; sq[t * 4 + 3] = q3;
    __syncthreads();
    if (t < TPN) {
#pragma unroll
        for (int sl = 1; sl < NPB; sl++) {
            int u = (sl * TPN + t) * 4;
            s0 += sm[u + 0]; s1 += sm[u + 1]; s2 += sm[u + 2]; s3 += sm[u + 3];
            q0 += sq[u + 0]; q1 += sq[u + 1]; q2 += sq[u + 2]; q3 += sq[u + 3];
        }
        atomicAdd(&gsum[t * 4 + 0], s0); atomicAdd(&gsum[t * 4 + 1], s1);
        atomicAdd(&gsum[t * 4 + 2], s2); atomicAdd(&gsum[t * 4 + 3], s3);
        atomicAdd(&gsumsq[t * 4 + 0], q0); atomicAdd(&gsumsq[t * 4 + 1], q1);
        atomicAdd(&gsumsq[t * 4 + 2], q2); atomicAdd(&gsumsq[t * 4 + 3], q3);
    }
}

// scale = g*rstd ; shift = be - mean*scale
__global__ void k_bn_finalize(const float* gsum, const float* gsumsq,
                              const float* g, const float* be,
                              float* sc, float* sh, int C) {
    int c = threadIdx.x;
    if (c < C) {
        const float invn = 1.0f / (float)N_NODES;
        float mean = gsum[c] * invn;
        float var = gsumsq[c] * invn - mean * mean;
        float rstd = rsqrtf(var + BN_EPS);
        float scale = g[c] * rstd;
        sc[c] = scale;
        sh[c] = fmaf(-mean, scale, be[c]);
    }
}

// ---------------------------------------------------------------------------
// GEMM2 (R3 version): h2s = (relu(bn1(out1)) @ W2) * dinv[row]
// 256 thr, 64-row tile (stride 132), thread = 4r x 4c, W2 from global.
// ---------------------------------------------------------------------------
__global__ __launch_bounds__(256) void k_gemm2(const float* __restrict__ out1,
                                               const float* __restrict__ sc1,
                                               const float* __restrict__ sh1,
                                               const float* __restrict__ W2,
                                               const float* __restrict__ dinv,
                                               float* __restrict__ h2s) {
    __shared__ float xs[64 * 132];  // 33.8 KB
    const int row0 = blockIdx.x * 64;
    const int t = threadIdx.x;
    {
        const float* src = out1 + (size_t)row0 * F_HID;
        const int maxe = (N_NODES - row0) * F_HID;
        for (int fi = t; fi < 64 * F_HID; fi += 256) {
            int r = fi >> 7;
            int c = fi & 127;
            float v = (fi < maxe) ? src[fi] : 0.0f;
            v = fmaf(v, sc1[c], sh1[c]);
            xs[r * 132 + c] = fmaxf(v, 0.0f);
        }
    }
    __syncthreads();

    const int c0 = (t & 15) * 4;
    const int r0 = (t >> 4) * 4;

    float acc[4][4];
#pragma unroll
    for (int r = 0; r < 4; r++)
#pragma unroll
        for (int c = 0; c < 4; c++) acc[r][c] = 0.0f;

#pragma unroll 2
    for (int k4 = 0; k4 < F_HID; k4 += 4) {
        float4 xv[4];
#pragma unroll
        for (int r = 0; r < 4; r++)
            xv[r] = *(const float4*)&xs[(r0 + r) * 132 + k4];
        float4 w[4];
#pragma unroll
        for (int j = 0; j < 4; j++)
            w[j] = *(const float4*)&W2[(k4 + j) * F_OUT + c0];
#pragma unroll
        for (int r = 0; r < 4; r++) {
            const float xr[4] = {xv[r].x, xv[r].y, xv[r].z, xv[r].w};
#pragma unroll
            for (int j = 0; j < 4; j++) {
                acc[r][0] = fmaf(xr[j], w[j].x, acc[r][0]);
                acc[r][1] = fmaf(xr[j], w[j].y, acc[r][1]);
                acc[r][2] = fmaf(xr[j], w[j].z, acc[r][2]);
                acc[r][3] = fmaf(xr[j], w[j].w, acc[r][3]);
            }
        }
    }
#pragma unroll
    for (int r = 0; r < 4; r++) {
        int row = row0 + r0 + r;
        if (row < N_NODES) {
            float dv = dinv[row];
            float4 o = {acc[r][0] * dv, acc[r][1] * dv, acc[r][2] * dv, acc[r][3] * dv};
            *(float4*)&h2s[(size_t)row * F_OUT + c0] = o;
        }
    }
}

// ---------------------------------------------------------------------------
// Final (R3 version): hf = bn2(out2) -> d_out; z = relu(hf@Wp1+bp1)@Wp2+bp2
// 256 thr, 64-row tile, two LDS GEMMs (K=64), thread = 4r x 4c.
// ---------------------------------------------------------------------------
__global__ __launch_bounds__(256) void k_final(const float* __restrict__ out2,
                                               const float* __restrict__ sc2,
                                               const float* __restrict__ sh2,
                                               const float* __restrict__ Wp1,
                                               const float* __restrict__ bp1,
                                               const float* __restrict__ Wp2,
                                               const float* __restrict__ bp2,
                                               float* __restrict__ out) {
    __shared__ float hs[64 * 68];   // 17.4 KB
    __shared__ float as_[64 * 68];  // 17.4 KB
    const int row0 = blockIdx.x * 64;
    const int t = threadIdx.x;

    {
        const float4* src = (const float4*)out2;
        float4* dsth = (float4*)out;
#pragma unroll
        for (int i = 0; i < 4; i++) {
            int f4 = t + i * 256;         // 0..1023
            int r = f4 >> 4;
            int c4 = f4 & 15;
            int grow = row0 + r;
            float4 v = {0, 0, 0, 0};
            if (grow < N_NODES) v = src[(size_t)grow * 16 + c4];
            int c = c4 * 4;
            v.x = fmaf(v.x, sc2[c + 0], sh2[c + 0]);
            v.y = fmaf(v.y, sc2[c + 1], sh2[c + 1]);
            v.z = fmaf(v.z, sc2[c + 2], sh2[c + 2]);
            v.w = fmaf(v.w, sc2[c + 3], sh2[c + 3]);
            if (grow < N_NODES) dsth[(size_t)grow * 16 + c4] = v;
            *(float4*)&hs[r * 68 + c] = v;
        }
    }
    __syncthreads();

    const int c0 = (t & 15) * 4;
    const int r0 = (t >> 4) * 4;

    // GEMM A: a = relu(hs @ Wp1 + bp1)
    {
        float acc[4][4];
#pragma unroll
        for (int r = 0; r < 4; r++)
#pragma unroll
            for (int c = 0; c < 4; c++) acc[r][c] = 0.0f;
#pragma unroll 2
        for (int k4 = 0; k4 < 64; k4 += 4) {
            float4 xv[4];
#pragma unroll
            for (int r = 0; r < 4; r++)
                xv[r] = *(const float4*)&hs[(r0 + r) * 68 + k4];
            float4 w[4];
#pragma unroll
            for (int j = 0; j < 4; j++)
                w[j] = *(const float4*)&Wp1[(k4 + j) * 64 + c0];
#pragma unroll
            for (int r = 0; r < 4; r++) {
                const float xr[4] = {xv[r].x, xv[r].y, xv[r].z, xv[r].w};
#pragma unroll
                for (int j = 0; j < 4; j++) {
                    acc[r][0] = fmaf(xr[j], w[j].x, acc[r][0]);
                    acc[r][1] = fmaf(xr[j], w[j].y, acc[r][1]);
                    acc[r][2] = fmaf(xr[j], w[j].z, acc[r][2]);
                    acc[r][3] = fmaf(xr[j], w[j].w, acc[r][3]);
                }
            }
        }
        float4 b = *(const float4*)&bp1[c0];
#pragma unroll
        for (int r = 0; r < 4; r++) {
            float4 o = {fmaxf(acc[r][0] + b.x, 0.0f), fmaxf(acc[r][1] + b.y, 0.0f),
                        fmaxf(acc[r][2] + b.z, 0.0f), fmaxf(acc[r][3] + b.w, 0.0f)};
            *(float4*)&as_[(r0 + r) * 68 + c0] = o;
        }
    }
    __syncthreads();

    // GEMM B: z = a @ Wp2 + bp2
    {
        float acc[4][4];
#pragma unroll
        for (int r = 0; r < 4; r++)
#pragma unroll
            for (int c = 0; c < 4; c++) acc[r][c] = 0.0f;
#pragma unroll 2
        for (int k4 = 0; k4 < 64; k4 += 4) {
            float4 xv[4];
#pragma unroll
            for (int r = 0; r < 4; r++)
                xv[r] = *(const float4*)&as_[(r0 + r) * 68 + k4];
            float4 w[4];
#pragma unroll
            for (int j = 0; j < 4; j++)
                w[j] = *(const float4*)&Wp2[(k4 + j) * 64 + c0];
#pragma unroll
            for (int r = 0; r < 4; r++) {
                const float xr[4] = {xv[r].x, xv[r].y, xv[r].z, xv[r].w};
#pragma unroll
                for (int j = 0; j < 4; j++) {
                    acc[r][0] = fmaf(xr[j], w[j].x, acc[r][0]);
                    acc[r][1] = fmaf(xr[j], w[j].y, acc[r][1]);
                    acc[r][2] = fmaf(xr[j], w[j].z, acc[r][2]);
                    acc[r][3] = fmaf(xr[j], w[j].w, acc[r][3]);
                }
            }
        }
        float4 b = *(const float4*)&bp2[c0];
        float* zout = out + (size_t)N_NODES * 64;
#pragma unroll
        for (int r = 0; r < 4; r++) {
            int row = row0 + r0 + r;
            if (row < N_NODES) {
                float4 o = {acc[r][0] + b.x, acc[r][1] + b.y,
                            acc[r][2] + b.z, acc[r][3] + b.w};
                *(float4*)&zout[(size_t)row * 64 + c0] = o;
            }
        }
    }
}

// ---------------------------------------------------------------------------
// launch
// ---------------------------------------------------------------------------
extern "C" void kernel_launch(void* const* d_in, const int* in_sizes, int n_in,
                              void* d_out, int out_size, void* d_ws, size_t ws_size,
                              hipStream_t stream) {
    const float* x   = (const float*)d_in[0];
    const int*   ei  = (const int*)d_in[1];
    const float* W1  = (const float*)d_in[2];
    // b1 (d_in[3]) skipped: column-constant shift cancelled by BN1
    const float* g1  = (const float*)d_in[4];
    const float* be1 = (const float*)d_in[5];
    const float* W2  = (const float*)d_in[6];
    // b2 (d_in[7]) skipped: cancelled by BN2
    const float* g2  = (const float*)d_in[8];
    const float* be2 = (const float*)d_in[9];
    const float* Wp1 = (const float*)d_in[10];
    const float* bp1 = (const float*)d_in[11];
    const float* Wp2 = (const float*)d_in[12];
    const float* bp2 = (const float*)d_in[13];

    const int* src = ei;            // edge_index[0]
    const int* dst = ei + N_EDGES;  // edge_index[1]

    float* ws = (float*)d_ws;
    float* A    = ws;                          // h1s (N*128) / h2s (N*64)
    float* B    = A + (size_t)N_NODES * 128;   // out1 (N*128) / out2 (N*64)
    float* dinv = B + (size_t)N_NODES * 128;   // N
    float* st   = dinv + N_NODES;              // 768 floats of stats
    float* s1   = st;        float* s1q  = st + 128;
    float* sc1  = st + 256;  float* sh1  = st + 384;
    float* s2   = st + 512;  float* s2q  = st + 576;
    float* sc2  = st + 640;  float* sh2  = st + 704;
    int* cnt      = (int*)(st + 768);          // N
    int* row_ptr  = cnt + N_NODES;             // N+1
    int* cursor   = row_ptr + N_NODES + 1;     // N
    int* csr_src  = cursor + N_NODES;          // E
    int* partials = csr_src + N_EDGES;         // NB_SCAN
    unsigned short* w1t = (unsigned short*)(partials + NB_SCAN);  // 128*192 bf16

    hipMemsetAsync(st, 0, (768 + N_NODES) * sizeof(float), stream);

    const int EB = (N_EDGES + 255) / 256;
    const int GB64 = (N_NODES + 63) / 64;
    const int GB128 = (N_NODES + 127) / 128;

    // CSR build + dinv (+ W1 conversion, independent)
    k_count<<<EB, 256, 0, stream>>>(dst, cnt);
    k_cvt_w<<<(F_HID * KP + 255) / 256, 256, 0, stream>>>(W1, w1t);
    k_scanA<<<NB_SCAN, 256, 0, stream>>>(cnt, partials);
    k_scanB<<<1, 1024, 0, stream>>>(partials, row_ptr);
    k_scanC<<<NB_SCAN, 256, 0, stream>>>(cnt, partials, row_ptr, cursor, dinv);
    k_scatter<<<EB, 256, 0, stream>>>(src, dst, cursor, csr_src);

    // layer 1 (MFMA bf16 GEMM)
    k_mfma1<<<GB128, 256, 0, stream>>>(x, w1t, dinv, A);
    k_aggr<128, 32, 8><<<1024, 256, 0, stream>>>(A, row_ptr, csr_src, dinv, B, s1, s1q);
    k_bn_finalize<<<1, 128, 0, stream>>>(s1, s1q, g1, be1, sc1, sh1, 128);

    // layer 2 (BN1+relu fused into GEMM2 load)
    k_gemm2<<<GB64, 256, 0, stream>>>(B, sc1, sh1, W2, dinv, A);
    k_aggr<64, 16, 16><<<1024, 256, 0, stream>>>(A, row_ptr, csr_src, dinv, B, s2, s2q);
    k_bn_finalize<<<1, 64, 0, stream>>>(s2, s2q, g2, be2, sc2, sh2, 64);

    // BN2-apply + MLP head, writes both outputs
    k_final<<<GB64, 256, 0, stream>>>(B, sc2, sh2, Wp1, bp1, Wp2, bp2, (float*)d_out);
}